// Round 8
// baseline (2251.517 us; speedup 1.0000x reference)
//
#include <hip/hip_runtime.h>

#define IN_CH 128
#define HIDDEN 64
#define BKT 128        // nodes per bucket (32KB LDS tile)
#define NBMAX 1024     // max coarse buckets

// ================= CSR-lite build: bucket (col>>7) grouping only ============
// Packed record (row<<7 | col&127) fits 24 bits (row < 2^17). No per-node
// sort pass needed: the gather accumulates via LDS float atomics. (R7 lesson:
// node-granular batching wastes slots/tail; stream edges per bucket instead.)

__global__ __launch_bounds__(1024)
void bucket_hist_kernel(const int* __restrict__ col, int* __restrict__ bhist, int E) {
    __shared__ int h[NBMAX];
    h[threadIdx.x] = 0;
    __syncthreads();
    const int start = blockIdx.x * 8192;
    const int end = min(start + 8192, E);
    for (int e = start + threadIdx.x; e < end; e += 1024)
        atomicAdd(&h[col[e] >> 7], 1);
    __syncthreads();
    if (h[threadIdx.x]) atomicAdd(&bhist[threadIdx.x], h[threadIdx.x]);
}

__global__ __launch_bounds__(1024)
void bucket_scan_kernel(const int* __restrict__ bhist, int* __restrict__ bbase,
                        int* __restrict__ bpos, int E) {
    __shared__ int s[NBMAX];
    const int t = threadIdx.x;
    const int v = bhist[t];          // bins >= nb are zero
    s[t] = v;
    __syncthreads();
    for (int d = 1; d < 1024; d <<= 1) {
        int u = (t >= d) ? s[t - d] : 0;
        __syncthreads();
        s[t] += u;
        __syncthreads();
    }
    const int b = s[t] - v;          // exclusive prefix
    bbase[t] = b;
    bpos[t] = b;
    if (t == 0) bbase[NBMAX] = E;
}

__global__ __launch_bounds__(1024)
void bucket_scatter_kernel(const int* __restrict__ row, const int* __restrict__ col,
                           int* __restrict__ bpos, unsigned* __restrict__ tmp, int E) {
    __shared__ int h[NBMAX];
    __shared__ int base[NBMAX];
    h[threadIdx.x] = 0;
    __syncthreads();
    const int start = blockIdx.x * 8192;
    const int end = min(start + 8192, E);
    for (int e = start + threadIdx.x; e < end; e += 1024)
        atomicAdd(&h[col[e] >> 7], 1);
    __syncthreads();
    const int i = threadIdx.x;
    base[i] = h[i] ? atomicAdd(&bpos[i], h[i]) : 0;
    h[i] = 0;
    __syncthreads();
    for (int e = start + threadIdx.x; e < end; e += 1024) {
        const int c = col[e];
        const int bk = c >> 7;
        const int p = base[bk] + atomicAdd(&h[bk], 1);
        tmp[p] = ((unsigned)row[e] << 7) | (unsigned)(c & 127);
    }
}

// per-bucket degree histogram -> dinv (deg = 1 self-loop + in-degree)
__global__ __launch_bounds__(256)
void deg_kernel(const unsigned* __restrict__ tmp, const int* __restrict__ bbase,
                float* __restrict__ dinv, int N) {
    __shared__ int cnt[BKT];
    const int b = blockIdx.x, t = threadIdx.x;
    if (t < BKT) cnt[t] = 0;
    __syncthreads();
    const int lo = bbase[b], hi = bbase[b + 1];
    for (int j = lo + t; j < hi; j += 256)
        atomicAdd(&cnt[tmp[j] & 127u], 1);
    __syncthreads();
    const int node = (b << 7) + t;
    if (t < BKT && node < N)
        dinv[node] = rsqrtf((float)cnt[t] + 1.0f);
}

// ---------------- tiled fp32 GEMM: Hs[N,64] = (X[N,K] @ W[K,64]) * dinv[n] ---

template <int K>
__global__ __launch_bounds__(256)
void gemm_kernel(const float* __restrict__ X, const float* __restrict__ W,
                 const float* __restrict__ dinv, float* __restrict__ Hs, int N) {
    constexpr int BK = 16;
    __shared__ float xs[BK][64];
    __shared__ float ws[BK][64];
    const int tid  = threadIdx.x;
    const int row0 = blockIdx.x * 64;
    const int tx4  = (tid & 15) << 2;
    const int ty4  = (tid >> 4) << 2;
    const int lrow = tid >> 2;
    const int kq   = (tid & 3) << 2;
    const int wk   = tid >> 4;
    const int wc   = (tid & 15) << 2;
    int grow = row0 + lrow;
    if (grow >= N) grow = N - 1;

    float acc[4][4] = {};
    for (int k0 = 0; k0 < K; k0 += BK) {
        const float4 xv = *reinterpret_cast<const float4*>(&X[(size_t)grow * K + k0 + kq]);
        const float4 wv = *reinterpret_cast<const float4*>(&W[(size_t)(k0 + wk) * 64 + wc]);
        __syncthreads();
        xs[kq + 0][lrow] = xv.x;
        xs[kq + 1][lrow] = xv.y;
        xs[kq + 2][lrow] = xv.z;
        xs[kq + 3][lrow] = xv.w;
        *reinterpret_cast<float4*>(&ws[wk][wc]) = wv;
        __syncthreads();
#pragma unroll
        for (int k = 0; k < BK; ++k) {
            const float4 a = *reinterpret_cast<const float4*>(&xs[k][ty4]);
            const float4 b = *reinterpret_cast<const float4*>(&ws[k][tx4]);
            const float av[4] = {a.x, a.y, a.z, a.w};
            const float bv[4] = {b.x, b.y, b.z, b.w};
#pragma unroll
            for (int r = 0; r < 4; ++r)
#pragma unroll
                for (int c = 0; c < 4; ++c)
                    acc[r][c] = fmaf(av[r], bv[c], acc[r][c]);
        }
    }
#pragma unroll
    for (int r = 0; r < 4; ++r) {
        int n = row0 + ty4 + r;
        if (n < N) {
            const float dn = dinv[n];
            float4 v = make_float4(acc[r][0] * dn, acc[r][1] * dn,
                                   acc[r][2] * dn, acc[r][3] * dn);
            *reinterpret_cast<float4*>(&Hs[(size_t)n * 64 + tx4]) = v;
        }
    }
}

// ---------------- push-stream aggregation into a 128-node LDS tile ----------
// One block per bucket; 8 waves stream contiguous edge slices (unroll 8:
// 8 record loads, 8 independent row loads, 8 native ds-f32 atomics).
// lane = feature -> LDS addr (tgt*64+lane): 2 lanes/bank (conflict-free).
// Epilogue fuses self-term + bias (+ReLU).

template <bool RELU>
__global__ __launch_bounds__(512)
void gather_lds_kernel(const float* __restrict__ Hs, const float* __restrict__ dinv,
                       const unsigned* __restrict__ tmp, const int* __restrict__ bbase,
                       const float* __restrict__ bias, float* __restrict__ A, int N) {
    __shared__ float acc[BKT * 64];   // 32 KB
    const int tid  = threadIdx.x;
    const int lane = tid & 63;
    const int b    = blockIdx.x;
    const int node0 = b << 7;
#pragma unroll
    for (int i = tid; i < BKT * 64; i += 512) acc[i] = 0.f;
    __syncthreads();

    const int lo = bbase[b], hi = bbase[b + 1];
    const int len = hi - lo;
    const int wid = __builtin_amdgcn_readfirstlane(tid >> 6);   // wave id 0..7
    int j        = lo + (len * wid) / 8;
    const int s1 = lo + (len * (wid + 1)) / 8;

    for (; j + 8 <= s1; j += 8) {
        unsigned pk[8];
#pragma unroll
        for (int u = 0; u < 8; ++u) pk[u] = tmp[j + u];
        float h[8];
#pragma unroll
        for (int u = 0; u < 8; ++u) h[u] = Hs[(size_t)(pk[u] >> 7) * 64 + lane];
#pragma unroll
        for (int u = 0; u < 8; ++u)
            atomicAdd(&acc[(pk[u] & 127u) * 64 + lane], h[u]);
    }
    for (; j < s1; ++j) {
        const unsigned pk = tmp[j];
        atomicAdd(&acc[(pk & 127u) * 64 + lane], Hs[(size_t)(pk >> 7) * 64 + lane]);
    }
    __syncthreads();

    const float bl = bias[lane];
    for (int t = wid; t < BKT; t += 8) {
        const int c = node0 + t;
        if (c >= N) break;
        const float dc = dinv[c];
        float o = dc * (acc[t * 64 + lane] + Hs[(size_t)c * 64 + lane]) + bl;
        if (RELU) o = fmaxf(o, 0.f);
        A[(size_t)c * 64 + lane] = o;
    }
}

// ---------------- mean-pool (batch is sorted) + final linear ----------------

__global__ __launch_bounds__(256)
void pool_kernel(const float* __restrict__ A, const int* __restrict__ batch,
                 float* __restrict__ pooled, int* __restrict__ gcnt, int N) {
    const int g = blockIdx.x >> 3;
    const int stripe = blockIdx.x & 7;
    int lo = 0, hi = N;
    while (lo < hi) { int m = (lo + hi) >> 1; if (batch[m] < g) lo = m + 1; else hi = m; }
    const int beg = lo;
    lo = beg; hi = N;
    while (lo < hi) { int m = (lo + hi) >> 1; if (batch[m] < g + 1) lo = m + 1; else hi = m; }
    const int end = lo;

    const int lane = threadIdx.x & 63;
    const int wsid = stripe * 4 + (threadIdx.x >> 6);
    float acc = 0.f;
    for (int i = beg + wsid; i < end; i += 32)
        acc += A[(size_t)i * 64 + lane];
    atomicAdd(&pooled[g * 64 + lane], acc);
    if (stripe == 0 && threadIdx.x == 0) gcnt[g] = end - beg;
}

__global__ void final_kernel(const float* __restrict__ pooled, const int* __restrict__ gcnt,
                             const float* __restrict__ Wlin, const float* __restrict__ blin,
                             float* __restrict__ out) {
    const int t = threadIdx.x;
    const int g = t >> 1, o = t & 1;
    const float c = (float)max(gcnt[g], 1);
    float acc = 0.f;
    for (int k = 0; k < 64; ++k)
        acc = fmaf(pooled[g * 64 + k], Wlin[k * 2 + o], acc);
    out[g * 2 + o] = acc / c + blin[o];
}

// ---------------- launch ----------------

extern "C" void kernel_launch(void* const* d_in, const int* in_sizes, int n_in,
                              void* d_out, int out_size, void* d_ws, size_t ws_size,
                              hipStream_t stream) {
    const float* x     = (const float*)d_in[0];
    const int*   ei    = (const int*)d_in[1];
    const int*   batch = (const int*)d_in[2];
    const float* W1    = (const float*)d_in[3];
    const float* b1    = (const float*)d_in[4];
    const float* W2    = (const float*)d_in[5];
    const float* b2    = (const float*)d_in[6];
    const float* W3    = (const float*)d_in[7];
    const float* b3    = (const float*)d_in[8];
    const float* Wlin  = (const float*)d_in[9];
    const float* blin  = (const float*)d_in[10];

    const int N = in_sizes[0] / IN_CH;
    const int E = in_sizes[1] / 2;
    const int* row = ei;
    const int* col = ei + E;
    const int nb = (N + BKT - 1) / BKT;   // 782 buckets for N=100k

    char* p = (char*)d_ws;
    auto alloc = [&](size_t bytes) {
        char* q = p;
        p += (bytes + 511) & ~(size_t)511;
        return q;
    };
    float*    dinv   = (float*)alloc((size_t)N * 4);
    unsigned* tmp    = (unsigned*)alloc((size_t)E * 4);
    float*    Hbuf   = (float*)alloc((size_t)N * HIDDEN * 4);
    float*    Abuf   = (float*)alloc((size_t)N * HIDDEN * 4);
    int*      bhist  = (int*)alloc(NBMAX * 4);
    int*      bbase  = (int*)alloc((NBMAX + 1) * 4);
    int*      bpos   = (int*)alloc(NBMAX * 4);
    float*    pooled = (float*)alloc(64 * 64 * 4);
    int*      gcnt   = (int*)alloc(64 * 4);
    (void)ws_size; (void)n_in; (void)out_size;

    // --- bucket grouping (no per-node sort; gather uses LDS atomics) ---
    hipMemsetAsync(bhist, 0, NBMAX * 4, stream);
    const int eb = (E + 8191) / 8192;
    bucket_hist_kernel<<<eb, 1024, 0, stream>>>(col, bhist, E);
    bucket_scan_kernel<<<1, 1024, 0, stream>>>(bhist, bbase, bpos, E);
    bucket_scatter_kernel<<<eb, 1024, 0, stream>>>(row, col, bpos, tmp, E);
    deg_kernel<<<nb, 256, 0, stream>>>(tmp, bbase, dinv, N);

    // --- 3 GCN layers ---
    const int gemm_grid = (N + 63) / 64;
    gemm_kernel<IN_CH><<<gemm_grid, 256, 0, stream>>>(x, W1, dinv, Hbuf, N);
    gather_lds_kernel<true><<<nb, 512, 0, stream>>>(Hbuf, dinv, tmp, bbase, b1, Abuf, N);
    gemm_kernel<HIDDEN><<<gemm_grid, 256, 0, stream>>>(Abuf, W2, dinv, Hbuf, N);
    gather_lds_kernel<true><<<nb, 512, 0, stream>>>(Hbuf, dinv, tmp, bbase, b2, Abuf, N);
    gemm_kernel<HIDDEN><<<gemm_grid, 256, 0, stream>>>(Abuf, W3, dinv, Hbuf, N);
    gather_lds_kernel<false><<<nb, 512, 0, stream>>>(Hbuf, dinv, tmp, bbase, b3, Abuf, N);

    // --- mean pool + final linear ---
    hipMemsetAsync(pooled, 0, 64 * 64 * 4, stream);
    pool_kernel<<<512, 256, 0, stream>>>(Abuf, batch, pooled, gcnt, N);
    final_kernel<<<1, 128, 0, stream>>>(pooled, gcnt, Wlin, blin, (float*)d_out);
}

// Round 9
// 414.671 us; speedup vs baseline: 5.4296x; 5.4296x over previous
//
#include <hip/hip_runtime.h>

#define IN_CH 128
#define HIDDEN 64

// ================= CSR build: two-level LDS-binned counting sort ============
// bucket = col >> 8 (256-node ranges). Packed record (row<<8 | col&255) fits
// 32 bits since row < 2^17 for N=100k. Avoids the 16x write-amplification of
// a direct random 4B scatter (R2 profile: fill_kernel wrote 105MB for 6.4MB).

__global__ __launch_bounds__(512)
void bucket_hist_kernel(const int* __restrict__ col, int* __restrict__ bhist, int E) {
    __shared__ int h[512];
    h[threadIdx.x] = 0;
    __syncthreads();
    const int start = blockIdx.x * 8192;
    const int end = min(start + 8192, E);
    for (int e = start + threadIdx.x; e < end; e += 512)
        atomicAdd(&h[col[e] >> 8], 1);
    __syncthreads();
    if (h[threadIdx.x]) atomicAdd(&bhist[threadIdx.x], h[threadIdx.x]);
}

__global__ __launch_bounds__(512)
void bucket_scan_kernel(const int* __restrict__ bhist, int* __restrict__ bbase,
                        int* __restrict__ bpos, int* __restrict__ off,
                        int nb, int N, int E) {
    __shared__ int s[512];
    const int t = threadIdx.x;
    const int v = (t < nb) ? bhist[t] : 0;
    s[t] = v;
    __syncthreads();
    for (int d = 1; d < 512; d <<= 1) {
        int u = (t >= d) ? s[t - d] : 0;
        __syncthreads();
        s[t] += u;
        __syncthreads();
    }
    const int b = s[t] - v;   // exclusive
    if (t < nb) { bbase[t] = b; bpos[t] = b; }
    if (t == 0) { bbase[nb] = E; off[N] = E; }
}

__global__ __launch_bounds__(512)
void bucket_scatter_kernel(const int* __restrict__ row, const int* __restrict__ col,
                           int* __restrict__ bpos, unsigned* __restrict__ tmp, int E) {
    __shared__ int h[512];
    __shared__ int base[512];
    h[threadIdx.x] = 0;
    __syncthreads();
    const int start = blockIdx.x * 8192;
    const int end = min(start + 8192, E);
    for (int e = start + threadIdx.x; e < end; e += 512)
        atomicAdd(&h[col[e] >> 8], 1);
    __syncthreads();
    const int i = threadIdx.x;
    base[i] = h[i] ? atomicAdd(&bpos[i], h[i]) : 0;
    h[i] = 0;
    __syncthreads();
    for (int e = start + threadIdx.x; e < end; e += 512) {
        const int c = col[e];
        const int bk = c >> 8;
        const int p = base[bk] + atomicAdd(&h[bk], 1);
        tmp[p] = ((unsigned)row[e] << 8) | (unsigned)(c & 255);
    }
}

__global__ __launch_bounds__(256)
void bucket_sort_kernel(const unsigned* __restrict__ tmp, const int* __restrict__ bbase,
                        int* __restrict__ off, float* __restrict__ dinv,
                        int* __restrict__ srcrow, int N) {
    __shared__ int cnt[256];
    __shared__ int sc[256];
    const int b = blockIdx.x;
    const int node0 = b << 8;
    const int t = threadIdx.x;
    const int lo = bbase[b], hi = bbase[b + 1];
    cnt[t] = 0;
    __syncthreads();
    for (int j = lo + t; j < hi; j += 256)
        atomicAdd(&cnt[tmp[j] & 255u], 1);
    __syncthreads();
    const int v = cnt[t];
    sc[t] = v;
    __syncthreads();
    for (int d = 1; d < 256; d <<= 1) {
        int u = (t >= d) ? sc[t - d] : 0;
        __syncthreads();
        sc[t] += u;
        __syncthreads();
    }
    const int excl = sc[t] - v;
    const int node = node0 + t;
    if (node < N) {
        off[node] = lo + excl;
        dinv[node] = rsqrtf((float)v + 1.0f);   // deg = 1 (self-loop) + in-degree
    }
    cnt[t] = lo + excl;   // reuse as running write cursor
    __syncthreads();
    for (int j = lo + t; j < hi; j += 256) {
        const unsigned pk = tmp[j];
        const int p = atomicAdd(&cnt[pk & 255u], 1);
        srcrow[p] = (int)(pk >> 8);
    }
}

// ---------------- tiled fp32 GEMM: Hs[N,64] = (X[N,K] @ W[K,64]) * dinv[n] ---

template <int K>
__global__ __launch_bounds__(256)
void gemm_kernel(const float* __restrict__ X, const float* __restrict__ W,
                 const float* __restrict__ dinv, float* __restrict__ Hs, int N) {
    constexpr int BK = 16;
    __shared__ float xs[BK][64];
    __shared__ float ws[BK][64];
    const int tid  = threadIdx.x;
    const int row0 = blockIdx.x * 64;
    const int tx4  = (tid & 15) << 2;
    const int ty4  = (tid >> 4) << 2;
    const int lrow = tid >> 2;
    const int kq   = (tid & 3) << 2;
    const int wk   = tid >> 4;
    const int wc   = (tid & 15) << 2;
    int grow = row0 + lrow;
    if (grow >= N) grow = N - 1;

    float acc[4][4] = {};
    for (int k0 = 0; k0 < K; k0 += BK) {
        const float4 xv = *reinterpret_cast<const float4*>(&X[(size_t)grow * K + k0 + kq]);
        const float4 wv = *reinterpret_cast<const float4*>(&W[(size_t)(k0 + wk) * 64 + wc]);
        __syncthreads();
        xs[kq + 0][lrow] = xv.x;
        xs[kq + 1][lrow] = xv.y;
        xs[kq + 2][lrow] = xv.z;
        xs[kq + 3][lrow] = xv.w;
        *reinterpret_cast<float4*>(&ws[wk][wc]) = wv;
        __syncthreads();
#pragma unroll
        for (int k = 0; k < BK; ++k) {
            const float4 a = *reinterpret_cast<const float4*>(&xs[k][ty4]);
            const float4 b = *reinterpret_cast<const float4*>(&ws[k][tx4]);
            const float av[4] = {a.x, a.y, a.z, a.w};
            const float bv[4] = {b.x, b.y, b.z, b.w};
#pragma unroll
            for (int r = 0; r < 4; ++r)
#pragma unroll
                for (int c = 0; c < 4; ++c)
                    acc[r][c] = fmaf(av[r], bv[c], acc[r][c]);
        }
    }
#pragma unroll
    for (int r = 0; r < 4; ++r) {
        int n = row0 + ty4 + r;
        if (n < N) {
            const float dn = dinv[n];
            float4 v = make_float4(acc[r][0] * dn, acc[r][1] * dn,
                                   acc[r][2] * dn, acc[r][3] * dn);
            *reinterpret_cast<float4*>(&Hs[(size_t)n * 64 + tx4]) = v;
        }
    }
}

// ---------------- pull-style aggregation, fused self-term + bias (+ReLU) ----
// 2 nodes per wave via float2 lanes: lanes 0-31 = node A (2 feats/lane),
// lanes 32-63 = node B. One gather instruction fetches two 256B rows (8B/lane)
// -> half the per-edge instructions of R5's version and 2x bytes in flight
// per wave, while keeping the large grid (12.5k blocks) that R8 showed is
// essential for MLP. Predication waste only ceil(max(degA,degB)/8) batches.

template <bool RELU>
__global__ __launch_bounds__(256)
void gather_kernel(const float* __restrict__ Hs, const float* __restrict__ dinv,
                   const int* __restrict__ off, const int* __restrict__ srcrow,
                   const float* __restrict__ bias, float* __restrict__ A, int N) {
    const int tid  = threadIdx.x;
    const int half = (tid & 63) >> 5;        // 0 = node A, 1 = node B
    const int fl   = (tid & 31) << 1;        // feature base (0,2,...,62)
    const int wid  = tid >> 6;               // wave 0..3
    const int c    = blockIdx.x * 8 + wid * 2 + half;
    const int cc   = (c < N) ? c : N - 1;    // clamp; store is guarded
    const int lo = off[cc], hi = off[cc + 1];

    float2 acc = make_float2(0.f, 0.f);
    int j = lo;
    while (__any(j < hi)) {
        int idx[8];
#pragma unroll
        for (int u = 0; u < 8; ++u) {
            const int jj = j + u;
            // hi>lo ? clamp into own range : harmless index 0
            idx[u] = srcrow[jj < hi ? jj : (hi > lo ? hi - 1 : 0)];
        }
        float2 h[8];
#pragma unroll
        for (int u = 0; u < 8; ++u)
            h[u] = *reinterpret_cast<const float2*>(&Hs[(size_t)idx[u] * 64 + fl]);
#pragma unroll
        for (int u = 0; u < 8; ++u) {
            if (j + u < hi) { acc.x += h[u].x; acc.y += h[u].y; }
        }
        j += 8;
    }

    if (c < N) {
        const float dc = dinv[c];
        const float2 hs = *reinterpret_cast<const float2*>(&Hs[(size_t)c * 64 + fl]);
        const float2 bl = *reinterpret_cast<const float2*>(&bias[fl]);
        float2 o;
        o.x = dc * (acc.x + hs.x) + bl.x;
        o.y = dc * (acc.y + hs.y) + bl.y;
        if (RELU) { o.x = fmaxf(o.x, 0.f); o.y = fmaxf(o.y, 0.f); }
        *reinterpret_cast<float2*>(&A[(size_t)c * 64 + fl]) = o;
    }
}

// ---------------- mean-pool (batch is sorted) + final linear ----------------

__global__ __launch_bounds__(256)
void pool_kernel(const float* __restrict__ A, const int* __restrict__ batch,
                 float* __restrict__ pooled, int* __restrict__ gcnt, int N) {
    const int g = blockIdx.x >> 3;
    const int stripe = blockIdx.x & 7;
    int lo = 0, hi = N;
    while (lo < hi) { int m = (lo + hi) >> 1; if (batch[m] < g) lo = m + 1; else hi = m; }
    const int beg = lo;
    lo = beg; hi = N;
    while (lo < hi) { int m = (lo + hi) >> 1; if (batch[m] < g + 1) lo = m + 1; else hi = m; }
    const int end = lo;

    const int lane = threadIdx.x & 63;
    const int wsid = stripe * 4 + (threadIdx.x >> 6);
    float acc = 0.f;
    for (int i = beg + wsid; i < end; i += 32)
        acc += A[(size_t)i * 64 + lane];
    atomicAdd(&pooled[g * 64 + lane], acc);
    if (stripe == 0 && threadIdx.x == 0) gcnt[g] = end - beg;
}

__global__ void final_kernel(const float* __restrict__ pooled, const int* __restrict__ gcnt,
                             const float* __restrict__ Wlin, const float* __restrict__ blin,
                             float* __restrict__ out) {
    const int t = threadIdx.x;
    const int g = t >> 1, o = t & 1;
    const float c = (float)max(gcnt[g], 1);
    float acc = 0.f;
    for (int k = 0; k < 64; ++k)
        acc = fmaf(pooled[g * 64 + k], Wlin[k * 2 + o], acc);
    out[g * 2 + o] = acc / c + blin[o];
}

// ---------------- launch ----------------

extern "C" void kernel_launch(void* const* d_in, const int* in_sizes, int n_in,
                              void* d_out, int out_size, void* d_ws, size_t ws_size,
                              hipStream_t stream) {
    const float* x     = (const float*)d_in[0];
    const int*   ei    = (const int*)d_in[1];
    const int*   batch = (const int*)d_in[2];
    const float* W1    = (const float*)d_in[3];
    const float* b1    = (const float*)d_in[4];
    const float* W2    = (const float*)d_in[5];
    const float* b2    = (const float*)d_in[6];
    const float* W3    = (const float*)d_in[7];
    const float* b3    = (const float*)d_in[8];
    const float* Wlin  = (const float*)d_in[9];
    const float* blin  = (const float*)d_in[10];

    const int N = in_sizes[0] / IN_CH;
    const int E = in_sizes[1] / 2;
    const int* row = ei;
    const int* col = ei + E;
    const int nb = (N + 255) >> 8;   // coarse buckets (<=512)

    char* p = (char*)d_ws;
    auto alloc = [&](size_t bytes) {
        char* q = p;
        p += (bytes + 511) & ~(size_t)511;
        return q;
    };
    int*      off    = (int*)alloc((size_t)(N + 1) * 4);
    float*    dinv   = (float*)alloc((size_t)N * 4);
    int*      srcrow = (int*)alloc((size_t)E * 4);
    unsigned* tmp    = (unsigned*)alloc((size_t)E * 4);
    float*    Hbuf   = (float*)alloc((size_t)N * HIDDEN * 4);
    float*    Abuf   = (float*)alloc((size_t)N * HIDDEN * 4);
    int*      bhist  = (int*)alloc(512 * 4);
    int*      bbase  = (int*)alloc(513 * 4);
    int*      bpos   = (int*)alloc(512 * 4);
    float*    pooled = (float*)alloc(64 * 64 * 4);
    int*      gcnt   = (int*)alloc(64 * 4);
    (void)ws_size; (void)n_in; (void)out_size;

    // --- CSR build (bucket sort; also produces dinv for the GEMM epilogue) ---
    hipMemsetAsync(bhist, 0, 512 * 4, stream);
    const int eb = (E + 8191) / 8192;
    bucket_hist_kernel<<<eb, 512, 0, stream>>>(col, bhist, E);
    bucket_scan_kernel<<<1, 512, 0, stream>>>(bhist, bbase, bpos, off, nb, N, E);
    bucket_scatter_kernel<<<eb, 512, 0, stream>>>(row, col, bpos, tmp, E);
    bucket_sort_kernel<<<nb, 256, 0, stream>>>(tmp, bbase, off, dinv, srcrow, N);

    // --- 3 GCN layers ---
    const int gemm_grid   = (N + 63) / 64;
    const int gather_grid = (N + 7) / 8;   // 8 nodes per 256-thread block
    gemm_kernel<IN_CH><<<gemm_grid, 256, 0, stream>>>(x, W1, dinv, Hbuf, N);
    gather_kernel<true><<<gather_grid, 256, 0, stream>>>(Hbuf, dinv, off, srcrow, b1, Abuf, N);
    gemm_kernel<HIDDEN><<<gemm_grid, 256, 0, stream>>>(Abuf, W2, dinv, Hbuf, N);
    gather_kernel<true><<<gather_grid, 256, 0, stream>>>(Hbuf, dinv, off, srcrow, b2, Abuf, N);
    gemm_kernel<HIDDEN><<<gemm_grid, 256, 0, stream>>>(Abuf, W3, dinv, Hbuf, N);
    gather_kernel<false><<<gather_grid, 256, 0, stream>>>(Hbuf, dinv, off, srcrow, b3, Abuf, N);

    // --- mean pool + final linear ---
    hipMemsetAsync(pooled, 0, 64 * 64 * 4, stream);
    pool_kernel<<<512, 256, 0, stream>>>(Abuf, batch, pooled, gcnt, N);
    final_kernel<<<1, 128, 0, stream>>>(pooled, gcnt, Wlin, blin, (float*)d_out);
}